// Round 4
// baseline (40.790 us; speedup 1.0000x reference)
//
#include <hip/hip_runtime.h>

typedef float f32x4 __attribute__((ext_vector_type(4)));
typedef short s16x8 __attribute__((ext_vector_type(8)));
typedef unsigned int u32;

// fp32 -> bf16 round-to-nearest-even
__device__ __forceinline__ u32 f2bf(float x) {
    u32 u = __float_as_uint(x);
    return (u + 0x7FFFu + ((u >> 16) & 1u)) >> 16;
}
__device__ __forceinline__ u32 pk(float a, float b) {
    return f2bf(a) | (f2bf(b) << 16);
}
// XOR-swizzle inside a [64 rows][64 t] bf16 plane (128B rows), 16B granules.
__device__ __forceinline__ int swzW(int row, int t) {
    int g = ((row ^ (row >> 3)) & 7) << 3;
    return row * 64 + (t ^ g);
}

// WG = (py, px-quarter). Full W tile resident in LDS (read Ht ONCE);
// loop b-halves x t-tiles with a small prefetched A tile.
__global__ __launch_bounds__(512, 2)
void upsample_mfma_kernel(const float* __restrict__ yt,
                          const float* __restrict__ Ht,
                          const float* __restrict__ biases,
                          float* __restrict__ out)
{
    // W: [16 px][64 uu][64 t] bf16, XOR rows, plane pad +8 elems (anti-collapse)
    __shared__ __align__(16) unsigned short Wl[16 * 4104];   // 131328 B
    // A: [16 px][32 b][24 t] bf16 (padded rows, round-3-proven)
    __shared__ __align__(16) unsigned short Al[16 * 768];    //  24576 B

    const int wg  = blockIdx.x;
    const int nw  = (wg & 7) * 32 + (wg >> 3);   // XCD chunks: 8 py rows/XCD
    const int py  = nw >> 2;
    const int pxq = nw & 3;
    const int px0 = pxq * 16;
    const int tid = (int)threadIdx.x;

    // ---- A staging coords: lanes 0..3 cover 16 px (64B granule) ----
    const int a_pxg = tid & 3;
    const int a_b   = (tid >> 2) & 31;
    const int a_tg  = tid >> 7;                  // 0..3 -> 4 t each
    const float* a_base = yt + (size_t)a_b * 262144 + (size_t)py * 64 + px0
                        + a_pxg * 4 + (size_t)a_tg * 4 * 4096;

    // ---- W staging coords: 32 lanes = 512B contiguous per (t,uy) row ----
    const int w_cc = tid & 31;
    const int w_uy = (tid >> 5) & 7;
    const int w_th = tid >> 8;                   // 0..1 -> t-half of 8
    const float* w_base = Ht + ((size_t)py * 8 + w_uy) * 512 + pxq * 128 + w_cc * 4;
    const int w_px  = w_cc >> 1;
    const int w_uu0 = w_uy * 8 + (w_cc & 1) * 4;

    // ---- compute coords ----
    const int wv = tid >> 6;                     // wave owns px wv*2, wv*2+1
    const int l = tid & 63, r = l & 15, q = l >> 4;
    const bool qlo = (q < 2);                    // K=16 effective per tile
    const int qq = (q & 1) * 8;
    const s16x8 zz = (s16x8){0, 0, 0, 0, 0, 0, 0, 0};

    // ---- prologue: A-load(0), W stage (once), A-write(0) ----
    f32x4 v[4];
    #pragma unroll
    for (int j = 0; j < 4; ++j)
        v[j] = *(const f32x4*)(a_base + (size_t)j * 4096);

    #pragma unroll
    for (int rr = 0; rr < 4; ++rr) {
        const int t0 = rr * 16 + w_th * 8;
        f32x4 wv8[8];
        #pragma unroll
        for (int j = 0; j < 8; ++j)
            wv8[j] = *(const f32x4*)(w_base + (size_t)(t0 + j) * 262144);
        #pragma unroll
        for (int i = 0; i < 4; ++i) {
            uint4 g;
            g.x = pk(wv8[0][i], wv8[1][i]);
            g.y = pk(wv8[2][i], wv8[3][i]);
            g.z = pk(wv8[4][i], wv8[5][i]);
            g.w = pk(wv8[6][i], wv8[7][i]);
            *(uint4*)&Wl[w_px * 4104 + swzW(w_uu0 + i, t0)] = g;
        }
    }
    #pragma unroll
    for (int i = 0; i < 4; ++i)
        *(uint2*)&Al[(a_pxg * 4 + i) * 768 + a_b * 24 + a_tg * 4] =
            make_uint2(pk(v[0][i], v[1][i]), pk(v[2][i], v[3][i]));

    // ---- bias (shared by both b-halves) + acc init ----
    float bv[2][4];
    #pragma unroll
    for (int pxi = 0; pxi < 2; ++pxi) {
        const int p = py * 64 + px0 + wv * 2 + pxi;
        #pragma unroll
        for (int nb = 0; nb < 4; ++nb)
            bv[pxi][nb] = biases[p * 64 + nb * 16 + r];
    }
    f32x4 acc[2][2][4];
    #pragma unroll
    for (int pxi = 0; pxi < 2; ++pxi)
        #pragma unroll
        for (int mb = 0; mb < 2; ++mb)
            #pragma unroll
            for (int nb = 0; nb < 4; ++nb)
                acc[pxi][mb][nb] = (f32x4){bv[pxi][nb], bv[pxi][nb], bv[pxi][nb], bv[pxi][nb]};

    __syncthreads();

    // ---- main loop: i = bh*4 + tt ----
    #pragma unroll
    for (int i = 0; i < 8; ++i) {
        const int bh = i >> 2, tt = i & 3;

        if (i < 7) {   // T14: issue next A-tile loads before compute
            const int ni = i + 1;
            const float* ab = a_base + (size_t)(ni >> 2) * 32 * 262144
                                     + (size_t)(ni & 3) * 16 * 4096;
            #pragma unroll
            for (int j = 0; j < 4; ++j)
                v[j] = *(const f32x4*)(ab + (size_t)j * 4096);
        }

        // compute tile (bh, tt): [32b x 16t] x [16t x 64uu] per px
        #pragma unroll
        for (int pxi = 0; pxi < 2; ++pxi) {
            const unsigned short* ap = &Al[(wv * 2 + pxi) * 768];
            const unsigned short* wp = &Wl[(wv * 2 + pxi) * 4104];
            s16x8 af[2], bf[4];
            #pragma unroll
            for (int mb = 0; mb < 2; ++mb)
                af[mb] = qlo ? *(const s16x8*)&ap[(mb * 16 + r) * 24 + qq] : zz;
            #pragma unroll
            for (int nb = 0; nb < 4; ++nb)
                bf[nb] = qlo ? *(const s16x8*)&wp[swzW(nb * 16 + r, tt * 16 + qq)] : zz;
            #pragma unroll
            for (int mb = 0; mb < 2; ++mb)
                #pragma unroll
                for (int nb = 0; nb < 4; ++nb)
                    acc[pxi][mb][nb] = __builtin_amdgcn_mfma_f32_16x16x32_bf16(
                        af[mb], bf[nb], acc[pxi][mb][nb], 0, 0, 0);
        }

        if (tt == 3) {   // b-half finished: pixel-shuffle store (+ reinit)
            #pragma unroll
            for (int pxi = 0; pxi < 2; ++pxi) {
                const int px = px0 + wv * 2 + pxi;
                #pragma unroll
                for (int mb = 0; mb < 2; ++mb) {
                    #pragma unroll
                    for (int nb = 0; nb < 4; ++nb) {
                        const int n   = nb * 16 + r;
                        const int row = py * 8 + (n >> 3);
                        const int col = px * 8 + (n & 7);
                        float* ob = out + ((size_t)(bh * 32 + mb * 16 + q * 4) * 512 + row) * 512 + col;
                        #pragma unroll
                        for (int ii = 0; ii < 4; ++ii)
                            ob[(size_t)ii * 262144] = acc[pxi][mb][nb][ii];
                        if (bh == 0)
                            acc[pxi][mb][nb] = (f32x4){bv[pxi][nb], bv[pxi][nb],
                                                       bv[pxi][nb], bv[pxi][nb]};
                    }
                }
            }
        }

        __syncthreads();                  // everyone done reading Al
        if (i < 7) {
            #pragma unroll
            for (int ii = 0; ii < 4; ++ii)
                *(uint2*)&Al[(a_pxg * 4 + ii) * 768 + a_b * 24 + a_tg * 4] =
                    make_uint2(pk(v[0][ii], v[1][ii]), pk(v[2][ii], v[3][ii]));
            __syncthreads();              // Al ready for next compute
        }
    }
}

extern "C" void kernel_launch(void* const* d_in, const int* in_sizes, int n_in,
                              void* d_out, int out_size, void* d_ws, size_t ws_size,
                              hipStream_t stream) {
    const float* yt     = (const float*)d_in[0];
    const float* Ht     = (const float*)d_in[1];
    const float* biases = (const float*)d_in[2];
    float* out          = (float*)d_out;
    upsample_mfma_kernel<<<dim3(256), dim3(512), 0, stream>>>(yt, Ht, biases, out);
}

// Round 5
// 39.992 us; speedup vs baseline: 1.0199x; 1.0199x over previous
//
#include <hip/hip_runtime.h>

typedef float f32x4 __attribute__((ext_vector_type(4)));
typedef short s16x8 __attribute__((ext_vector_type(8)));
typedef unsigned int u32;

// fp32 -> bf16 round-to-nearest-even
__device__ __forceinline__ u32 f2bf(float x) {
    u32 u = __float_as_uint(x);
    return (u + 0x7FFFu + ((u >> 16) & 1u)) >> 16;
}
__device__ __forceinline__ u32 pk(float a, float b) {
    return f2bf(a) | (f2bf(b) << 16);
}
// XOR swizzle in a [rows][64 t] bf16 plane (128B rows), 16B (8-elem) granules.
__device__ __forceinline__ int swz(int row, int t) {
    int g = ((row ^ (row >> 3)) & 7) << 3;
    return row * 64 + (t ^ g);
}

// WG = (py, 8 px), 8 waves, wave = 1 px. W lives in REGISTERS (32 VGPR/wave)
// after a one-shot LDS bounce; the same 64KB LDS is then reused for the two
// 32-b A chunks (disjoint halves). 3 barriers total, 2 WG/CU.
__global__ __launch_bounds__(512, 4)
void upsample_mfma_kernel(const float* __restrict__ yt,
                          const float* __restrict__ Ht,
                          const float* __restrict__ biases,
                          float* __restrict__ out)
{
    // 64KB: first 8 W planes [px][64uu][64t]; after barrier#2 reused as
    // A chunks [bc][8px][32b][64t].
    __shared__ __align__(16) unsigned short S[32768];

    const int wg  = blockIdx.x;
    const int py  = (wg & 7) + ((wg >> 3) & 7) * 8;  // same py-row WGs -> same XCD
    const int pxo = wg >> 6;                         // 0..7
    const int px0 = pxo * 8;
    const int tid = (int)threadIdx.x;

    // ============ Phase 1: stage W (Ht slice) -> LDS, 256B-coalesced ============
    {
        const int c4 = tid & 15;          // 16 x f32x4 = 64 cols (256B rows)
        const int uy = (tid >> 4) & 7;
        const int tq = tid >> 7;          // 0..3
        const float* wb = Ht + (size_t)(py * 8 + uy) * 512 + px0 * 8 + c4 * 4;
        #pragma unroll
        for (int ph = 0; ph < 2; ++ph) {
            const int t0 = ph * 32 + tq * 8;
            f32x4 v[8];
            #pragma unroll
            for (int k = 0; k < 8; ++k)
                v[k] = *(const f32x4*)(wb + (size_t)(t0 + k) * 262144);
            #pragma unroll
            for (int cc = 0; cc < 4; ++cc) {
                const int c   = c4 * 4 + cc;
                const int pxl = c >> 3;
                const int uu  = uy * 8 + (c & 7);
                uint4 g;
                g.x = pk(v[0][cc], v[1][cc]);
                g.y = pk(v[2][cc], v[3][cc]);
                g.z = pk(v[4][cc], v[5][cc]);
                g.w = pk(v[6][cc], v[7][cc]);
                *(uint4*)&S[pxl * 4096 + swz(uu, t0)] = g;
            }
        }
    }
    __syncthreads();

    // ============ Phase 2: W frags -> registers (per wave = per px) ============
    const int wv = tid >> 6;
    const int l = tid & 63, r = l & 15, q = l >> 4;
    s16x8 wf[4][2];
    #pragma unroll
    for (int nb = 0; nb < 4; ++nb)
        #pragma unroll
        for (int ks = 0; ks < 2; ++ks)
            wf[nb][ks] = *(const s16x8*)&S[wv * 4096 + swz(nb * 16 + r, ks * 32 + q * 8)];

    const int px = px0 + wv;
    const int p  = py * 64 + px;
    float bv[4];
    #pragma unroll
    for (int nb = 0; nb < 4; ++nb)
        bv[nb] = biases[(size_t)p * 64 + nb * 16 + r];

    __syncthreads();   // all W frag reads done -> LDS reusable

    // ============ Phase 3: stage BOTH A chunks (yt), 32B granules ============
    {
        const int pxh = tid & 1;
        const int ab  = (tid >> 1) & 31;
        const int atq = tid >> 6;          // 0..7
        const float* abase = yt + (size_t)py * 64 + px0 + pxh * 4
                           + (size_t)atq * 8 * 4096;
        #pragma unroll
        for (int bc = 0; bc < 2; ++bc) {
            const float* ap = abase + (size_t)(bc * 32 + ab) * 262144;
            f32x4 v[8];
            #pragma unroll
            for (int k = 0; k < 8; ++k)
                v[k] = *(const f32x4*)(ap + (size_t)k * 4096);
            #pragma unroll
            for (int i = 0; i < 4; ++i) {
                uint4 g;
                g.x = pk(v[0][i], v[1][i]);
                g.y = pk(v[2][i], v[3][i]);
                g.z = pk(v[4][i], v[5][i]);
                g.w = pk(v[6][i], v[7][i]);
                *(uint4*)&S[bc * 16384 + (pxh * 4 + i) * 2048 + swz(ab, atq * 8)] = g;
            }
        }
    }
    __syncthreads();

    // ============ Phase 4: compute + pixel-shuffle store ============
    #pragma unroll
    for (int bc = 0; bc < 2; ++bc) {
        f32x4 acc[2][4];
        #pragma unroll
        for (int mb = 0; mb < 2; ++mb)
            #pragma unroll
            for (int nb = 0; nb < 4; ++nb)
                acc[mb][nb] = (f32x4){bv[nb], bv[nb], bv[nb], bv[nb]};

        #pragma unroll
        for (int ks = 0; ks < 2; ++ks) {
            s16x8 af[2];
            #pragma unroll
            for (int mb = 0; mb < 2; ++mb)
                af[mb] = *(const s16x8*)&S[bc * 16384 + wv * 2048
                                           + swz(mb * 16 + r, ks * 32 + q * 8)];
            #pragma unroll
            for (int mb = 0; mb < 2; ++mb)
                #pragma unroll
                for (int nb = 0; nb < 4; ++nb)
                    acc[mb][nb] = __builtin_amdgcn_mfma_f32_16x16x32_bf16(
                        af[mb], wf[nb][ks], acc[mb][nb], 0, 0, 0);
        }

        #pragma unroll
        for (int mb = 0; mb < 2; ++mb) {
            #pragma unroll
            for (int nb = 0; nb < 4; ++nb) {
                const int n   = nb * 16 + r;
                const int row = py * 8 + (n >> 3);
                const int col = px * 8 + (n & 7);
                float* ob = out + ((size_t)(bc * 32 + mb * 16 + q * 4) * 512 + row) * 512 + col;
                #pragma unroll
                for (int ii = 0; ii < 4; ++ii)
                    ob[(size_t)ii * 262144] = acc[mb][nb][ii];
            }
        }
    }
}

extern "C" void kernel_launch(void* const* d_in, const int* in_sizes, int n_in,
                              void* d_out, int out_size, void* d_ws, size_t ws_size,
                              hipStream_t stream) {
    const float* yt     = (const float*)d_in[0];
    const float* Ht     = (const float*)d_in[1];
    const float* biases = (const float*)d_in[2];
    float* out          = (float*)d_out;
    upsample_mfma_kernel<<<dim3(512), dim3(512), 0, stream>>>(yt, Ht, biases, out);
}

// Round 6
// 38.170 us; speedup vs baseline: 1.0687x; 1.0478x over previous
//
#include <hip/hip_runtime.h>

typedef float f32x4 __attribute__((ext_vector_type(4)));
typedef short s16x8 __attribute__((ext_vector_type(8)));
typedef unsigned int u32;

// fp32 -> bf16 round-to-nearest-even
__device__ __forceinline__ u32 f2bf(float x) {
    u32 u = __float_as_uint(x);
    return (u + 0x7FFFu + ((u >> 16) & 1u)) >> 16;
}
__device__ __forceinline__ u32 pk(float a, float b) {
    return f2bf(a) | (f2bf(b) << 16);
}
// XOR swizzle in a [rows][64 t] bf16 plane (128B rows), 16B (8-elem) granules.
__device__ __forceinline__ int swz(int row, int t) {
    int g = ((row ^ (row >> 3)) & 7) << 3;
    return row * 64 + (t ^ g);
}
// bounce-buffer granule hash (f32 plane, rows of 64 f32 = 16 granules)
__device__ __forceinline__ int bh(int rowid) {
    return (rowid ^ (rowid >> 4)) & 15;
}

// r5 structure (W-in-registers, 3-phase staging) + LDS-bounced COALESCED
// epilogue: every global store is a full 256B-run f32x4 wave store.
__global__ __launch_bounds__(512, 4)
void upsample_mfma_kernel(const float* __restrict__ yt,
                          const float* __restrict__ Ht,
                          const float* __restrict__ biases,
                          float* __restrict__ out)
{
    // 64KB: W planes -> A chunks -> f32 bounce buffer
    __shared__ __align__(16) unsigned short S[32768];

    const int wg  = blockIdx.x;
    const int py  = (wg & 7) + ((wg >> 3) & 7) * 8;
    const int pxo = wg >> 6;                         // 0..7
    const int px0 = pxo * 8;
    const int tid = (int)threadIdx.x;

    // ============ Phase 1: stage W (Ht slice) -> LDS, 256B-coalesced ============
    {
        const int c4 = tid & 15;
        const int uy = (tid >> 4) & 7;
        const int tq = tid >> 7;
        const float* wb = Ht + (size_t)(py * 8 + uy) * 512 + px0 * 8 + c4 * 4;
        #pragma unroll
        for (int ph = 0; ph < 2; ++ph) {
            const int t0 = ph * 32 + tq * 8;
            f32x4 v[8];
            #pragma unroll
            for (int k = 0; k < 8; ++k)
                v[k] = *(const f32x4*)(wb + (size_t)(t0 + k) * 262144);
            #pragma unroll
            for (int cc = 0; cc < 4; ++cc) {
                const int c   = c4 * 4 + cc;
                const int pxl = c >> 3;
                const int uu  = uy * 8 + (c & 7);
                uint4 g;
                g.x = pk(v[0][cc], v[1][cc]);
                g.y = pk(v[2][cc], v[3][cc]);
                g.z = pk(v[4][cc], v[5][cc]);
                g.w = pk(v[6][cc], v[7][cc]);
                *(uint4*)&S[pxl * 4096 + swz(uu, t0)] = g;
            }
        }
    }
    __syncthreads();

    // ============ Phase 2: W frags -> registers (per wave = per px) ============
    const int wv = tid >> 6;
    const int l = tid & 63, r = l & 15, q = l >> 4;
    s16x8 wf[4][2];
    #pragma unroll
    for (int nb = 0; nb < 4; ++nb)
        #pragma unroll
        for (int ks = 0; ks < 2; ++ks)
            wf[nb][ks] = *(const s16x8*)&S[wv * 4096 + swz(nb * 16 + r, ks * 32 + q * 8)];

    const int px = px0 + wv;
    const int p  = py * 64 + px;
    float bv[4];
    #pragma unroll
    for (int nb = 0; nb < 4; ++nb)
        bv[nb] = biases[(size_t)p * 64 + nb * 16 + r];

    __syncthreads();   // all W frag reads done -> LDS reusable

    // ============ Phase 3: stage BOTH A chunks (yt), 32B granules ============
    {
        const int pxh = tid & 1;
        const int ab  = (tid >> 1) & 31;
        const int atq = tid >> 6;
        const float* abase = yt + (size_t)py * 64 + px0 + pxh * 4
                           + (size_t)atq * 8 * 4096;
        #pragma unroll
        for (int bc = 0; bc < 2; ++bc) {
            const float* ap = abase + (size_t)(bc * 32 + ab) * 262144;
            f32x4 v[8];
            #pragma unroll
            for (int k = 0; k < 8; ++k)
                v[k] = *(const f32x4*)(ap + (size_t)k * 4096);
            #pragma unroll
            for (int i = 0; i < 4; ++i) {
                uint4 g;
                g.x = pk(v[0][i], v[1][i]);
                g.y = pk(v[2][i], v[3][i]);
                g.z = pk(v[4][i], v[5][i]);
                g.w = pk(v[6][i], v[7][i]);
                *(uint4*)&S[bc * 16384 + (pxh * 4 + i) * 2048 + swz(ab, atq * 8)] = g;
            }
        }
    }
    __syncthreads();

    // ============ Phase 4: compute BOTH b-chunks, acc in registers ============
    f32x4 acc[2][2][4];
    #pragma unroll
    for (int bc = 0; bc < 2; ++bc)
        #pragma unroll
        for (int mb = 0; mb < 2; ++mb)
            #pragma unroll
            for (int nb = 0; nb < 4; ++nb)
                acc[bc][mb][nb] = (f32x4){bv[nb], bv[nb], bv[nb], bv[nb]};

    #pragma unroll
    for (int bc = 0; bc < 2; ++bc) {
        #pragma unroll
        for (int ks = 0; ks < 2; ++ks) {
            s16x8 af[2];
            #pragma unroll
            for (int mb = 0; mb < 2; ++mb)
                af[mb] = *(const s16x8*)&S[bc * 16384 + wv * 2048
                                           + swz(mb * 16 + r, ks * 32 + q * 8)];
            #pragma unroll
            for (int mb = 0; mb < 2; ++mb)
                #pragma unroll
                for (int nb = 0; nb < 4; ++nb)
                    acc[bc][mb][nb] = __builtin_amdgcn_mfma_f32_16x16x32_bf16(
                        af[mb], wf[nb][ks], acc[bc][mb][nb], 0, 0, 0);
        }
    }

    // ============ Phase 5: LDS-bounced coalesced epilogue ============
    // Bounce layout per bc: f32 [rowid = b*8+uy][64 cols], 16B granules XOR'd by bh(rowid).
    float* Sf = (float*)S;
    #pragma unroll
    for (int bc = 0; bc < 2; ++bc) {
        __syncthreads();   // prior S readers done (A frags / previous store pass)

        #pragma unroll
        for (int mb = 0; mb < 2; ++mb) {
            #pragma unroll
            for (int nb = 0; nb < 4; ++nb) {
                const int uy  = nb * 2 + (r >> 3);
                const int c4l = wv * 2 + ((r & 7) >> 2);
                const int e   = r & 3;
                #pragma unroll
                for (int ii = 0; ii < 4; ++ii) {
                    const int b     = mb * 16 + q * 4 + ii;
                    const int rowid = b * 8 + uy;
                    Sf[rowid * 64 + ((c4l ^ bh(rowid)) << 2) + e] = acc[bc][mb][nb][ii];
                }
            }
        }
        __syncthreads();

        // coalesced store: 8 x f32x4 per thread; each wave instr = 1KB in 256B runs
        #pragma unroll
        for (int j = 0; j < 8; ++j) {
            const int slot  = j * 512 + tid;       // 4096 f32x4 slots
            const int b     = slot >> 7;           // 128 slots per b
            const int rem   = slot & 127;
            const int uy    = rem >> 4;
            const int c4    = rem & 15;
            const int rowid = b * 8 + uy;
            f32x4 vv = *(const f32x4*)&Sf[rowid * 64 + ((c4 ^ bh(rowid)) << 2)];
            *(f32x4*)&out[((size_t)(bc * 32 + b) * 512 + py * 8 + uy) * 512
                          + px0 * 8 + c4 * 4] = vv;
        }
    }
}

extern "C" void kernel_launch(void* const* d_in, const int* in_sizes, int n_in,
                              void* d_out, int out_size, void* d_ws, size_t ws_size,
                              hipStream_t stream) {
    const float* yt     = (const float*)d_in[0];
    const float* Ht     = (const float*)d_in[1];
    const float* biases = (const float*)d_in[2];
    float* out          = (float*)d_out;
    upsample_mfma_kernel<<<dim3(512), dim3(512), 0, stream>>>(yt, Ht, biases, out);
}

// Round 7
// 36.635 us; speedup vs baseline: 1.1134x; 1.0419x over previous
//
#include <hip/hip_runtime.h>

typedef float f32x4 __attribute__((ext_vector_type(4)));
typedef short s16x8 __attribute__((ext_vector_type(8)));
typedef unsigned int u32;

__device__ __forceinline__ u32 f2bf(float x) {
    u32 u = __float_as_uint(x);
    return (u + 0x7FFFu + ((u >> 16) & 1u)) >> 16;
}
__device__ __forceinline__ u32 pk(float a, float b) {
    return f2bf(a) | (f2bf(b) << 16);
}
// W planes: [64 rows][64 t] bf16, XOR on 16B granules
__device__ __forceinline__ int swz(int row, int t) {
    int g = ((row ^ (row >> 3)) & 7) << 3;
    return row * 64 + (t ^ g);
}
// A planes: [16 rows][64 t] bf16
__device__ __forceinline__ int swzA(int row, int t) {
    return row * 64 + (t ^ ((row & 7) << 3));
}
// bounce granule hash ([128 rows][64 f32])
__device__ __forceinline__ int bh(int rowid) {
    return (rowid ^ (rowid >> 4)) & 15;
}

#define A_PLANE 1032          // shorts per A px-plane ([16][64] + 8 pad)
#define A_SLOT  (8 * A_PLANE) // 8256 shorts = 16512 B
#define BOUNCE  (2 * A_SLOT)  // short offset 16512 -> byte 33024 (16B aligned)

// r6 base + (a) py-contiguous XCD map, (b) 4-chunk b-pipeline interleaving
// reads/compute/stores, (c) early-issued yt loads.
__global__ __launch_bounds__(512, 4)
void upsample_mfma_kernel(const float* __restrict__ yt,
                          const float* __restrict__ Ht,
                          const float* __restrict__ biases,
                          float* __restrict__ out)
{
    __shared__ __align__(16) unsigned short S[32896];   // 65792 B

    const int wg  = blockIdx.x;
    const int xcd = wg & 7;
    const int j   = wg >> 3;
    const int py  = xcd * 8 + (j & 7);   // XCD k owns py in [8k, 8k+8)
    const int pxo = j >> 3;
    const int px0 = pxo * 8;
    const int tid = (int)threadIdx.x;

    // ---- A staging coords: 8px*4B = 32B runs, 2 lanes each ----
    const int pxh = tid & 1;
    const int ab  = (tid >> 1) & 15;     // b within 16-chunk
    const int atq = tid >> 5;            // 0..15, t = atq*4 + k
    const float* a_base = yt + (size_t)ab * 262144 + (size_t)atq * 4 * 4096
                        + py * 64 + px0 + pxh * 4;

    f32x4 v[4];
    // issue chunk-0 yt loads FIRST (land during Ht staging)
    #pragma unroll
    for (int k = 0; k < 4; ++k)
        v[k] = *(const f32x4*)(a_base + (size_t)k * 4096);

    // ============ Phase 1: stage W (Ht slice) -> LDS ============
    {
        const int c4 = tid & 15, uy = (tid >> 4) & 7, tq = tid >> 7;
        const float* wb = Ht + (size_t)(py * 8 + uy) * 512 + px0 * 8 + c4 * 4;
        #pragma unroll
        for (int ph = 0; ph < 2; ++ph) {
            const int t0 = ph * 32 + tq * 8;
            f32x4 w8[8];
            #pragma unroll
            for (int k = 0; k < 8; ++k)
                w8[k] = *(const f32x4*)(wb + (size_t)(t0 + k) * 262144);
            #pragma unroll
            for (int cc = 0; cc < 4; ++cc) {
                const int c = c4 * 4 + cc, pxl = c >> 3, uu = uy * 8 + (c & 7);
                uint4 g;
                g.x = pk(w8[0][cc], w8[1][cc]);
                g.y = pk(w8[2][cc], w8[3][cc]);
                g.z = pk(w8[4][cc], w8[5][cc]);
                g.w = pk(w8[6][cc], w8[7][cc]);
                *(uint4*)&S[pxl * 4096 + swz(uu, t0)] = g;
            }
        }
    }
    __syncthreads();

    // ============ Phase 2: W frags -> regs, bias ============
    const int wv = tid >> 6, l = tid & 63, r = l & 15, q = l >> 4;
    s16x8 wf[4][2];
    #pragma unroll
    for (int nb = 0; nb < 4; ++nb)
        #pragma unroll
        for (int ks = 0; ks < 2; ++ks)
            wf[nb][ks] = *(const s16x8*)&S[wv * 4096 + swz(nb * 16 + r, ks * 32 + q * 8)];
    const int px = px0 + wv, p = py * 64 + px;
    float bv[4];
    #pragma unroll
    for (int nb = 0; nb < 4; ++nb)
        bv[nb] = biases[(size_t)p * 64 + nb * 16 + r];
    __syncthreads();   // W reads done -> LDS reusable

    // ---- helpers ----
    auto writeA = [&](int slot) {
        #pragma unroll
        for (int pp = 0; pp < 4; ++pp) {
            const int pxl = pxh * 4 + pp;
            *(uint2*)&S[slot * A_SLOT + pxl * A_PLANE + swzA(ab, atq * 4)] =
                make_uint2(pk(v[0][pp], v[1][pp]), pk(v[2][pp], v[3][pp]));
        }
    };
    auto issueA = [&](int chunk) {
        const float* ap = a_base + (size_t)chunk * 16 * 262144;
        #pragma unroll
        for (int k = 0; k < 4; ++k)
            v[k] = *(const f32x4*)(ap + (size_t)k * 4096);
    };

    writeA(0);
    issueA(1);
    __syncthreads();

    float* Sf = (float*)&S[BOUNCE];

    // ============ pipelined main loop over 4 b-chunks ============
    #pragma unroll
    for (int i = 0; i < 4; ++i) {
        // compute chunk i (wave-local A plane)
        f32x4 acc[4];
        #pragma unroll
        for (int nb = 0; nb < 4; ++nb)
            acc[nb] = (f32x4){bv[nb], bv[nb], bv[nb], bv[nb]};
        #pragma unroll
        for (int ks = 0; ks < 2; ++ks) {
            s16x8 af = *(const s16x8*)&S[(i & 1) * A_SLOT + wv * A_PLANE
                                         + swzA(r, ks * 32 + q * 8)];
            #pragma unroll
            for (int nb = 0; nb < 4; ++nb)
                acc[nb] = __builtin_amdgcn_mfma_f32_16x16x32_bf16(
                    af, wf[nb][ks], acc[nb], 0, 0, 0);
        }

        if (i < 3) {
            writeA((i + 1) & 1);   // slot last read at compute(i-1): safe
            if (i < 2) issueA(i + 2);
        }

        // bounce acc -> Sf ([rowid = bl*8+uy][64 cols], XOR-hashed granules)
        #pragma unroll
        for (int nb = 0; nb < 4; ++nb) {
            const int uy  = nb * 2 + (r >> 3);
            const int c4l = wv * 2 + ((r & 7) >> 2);
            const int e   = r & 3;
            #pragma unroll
            for (int ii = 0; ii < 4; ++ii) {
                const int bl    = q * 4 + ii;
                const int rowid = bl * 8 + uy;
                Sf[rowid * 64 + ((c4l ^ bh(rowid)) << 2) + e] = acc[nb][ii];
            }
        }
        __syncthreads();

        // coalesced store: 2048 f32x4 slots, 4 per thread
        #pragma unroll
        for (int jj = 0; jj < 4; ++jj) {
            const int slot = jj * 512 + tid;
            const int bl = slot >> 7, rem = slot & 127;
            const int uy = rem >> 4, c4 = rem & 15;
            const int rowid = bl * 8 + uy;
            f32x4 vv = *(const f32x4*)&Sf[rowid * 64 + ((c4 ^ bh(rowid)) << 2)];
            *(f32x4*)&out[((size_t)(i * 16 + bl) * 512 + py * 8 + uy) * 512
                          + px0 * 8 + c4 * 4] = vv;
        }
        __syncthreads();
    }
}

extern "C" void kernel_launch(void* const* d_in, const int* in_sizes, int n_in,
                              void* d_out, int out_size, void* d_ws, size_t ws_size,
                              hipStream_t stream) {
    const float* yt     = (const float*)d_in[0];
    const float* Ht     = (const float*)d_in[1];
    const float* biases = (const float*)d_in[2];
    float* out          = (float*)d_out;
    upsample_mfma_kernel<<<dim3(512), dim3(512), 0, stream>>>(yt, Ht, biases, out);
}